// Round 1
// 893.930 us; speedup vs baseline: 1.1672x; 1.1672x over previous
//
#include <hip/hip_runtime.h>

// SubLSTM R5: 4-wave producer/consumer pipeline per chain (was 2-wave).
//  role0: stage x chunk -> LDS ring XS; layer0 input proj (Wih0*x+b) -> XW0 ring
//  role1: layer0 recurrence (Whh0*h + XW0) -> h0 -> H0 ring
//  role2: layer1 input proj (Wih1*h0+b) -> XW1 ring
//  role3: layer1 recurrence -> out = h1 + x residual
// 512 blocks x 256 thr = 2048 waves = 2 waves/SIMD (was 1) -> latency hiding.
// Role<->wave parity swap pairs a light proj wave with a heavy recurrent wave
// on each SIMD. Weights prescaled by log2e (2*log2e for g-gate rows) so all
// activations use raw v_exp_f32 (exp2) with no scaling mul.
// mlp_mfma unchanged.

#define Gn 8
#define Dn 20
#define Bn 64
#define Tn 2000
#define Fn 160
#define NR (Bn * Tn)
#define L2E 1.4426950408889634f

__device__ __forceinline__ float rdlane(float v, int k) {
  return __int_as_float(__builtin_amdgcn_readlane(__float_as_int(v), k));
}
__device__ __forceinline__ float sigm2(float x) {  // rcp(1+exp2(-x)); x pre-scaled by log2e
  return __builtin_amdgcn_rcpf(1.f + __builtin_amdgcn_exp2f(-x));
}
__device__ __forceinline__ unsigned short f2bf(float f) {
  unsigned u = __float_as_uint(f);
  u += 0x8000u;
  return (unsigned short)(u >> 16);
}

// gA = gates[lane] (0..63), gB = gates[64+(lane&15)] (lanes 0..15 valid).
// i,f,o rows prescaled by log2e; g rows by 2*log2e.
__device__ __forceinline__ void lstm_update2(float gA, float gB, int lane,
                                             float& h, float& c) {
  const float fg = __shfl(gA, (20 + lane) & 63);
  const float gg = __shfl(gA, (40 + lane) & 63);
  const float o1v = __shfl(gA, (60 + lane) & 63);
  const float o2v = __shfl(gB, (lane - 4) & 63);
  const float og = (lane < 4) ? o1v : o2v;
  const float sI = sigm2(gA);
  const float sF = sigm2(fg);
  const float sO = sigm2(og);
  // tanh(y) with gg = 2*log2e*y already folded in:
  const float tG = 1.f - 2.f * __builtin_amdgcn_rcpf(__builtin_amdgcn_exp2f(gg) + 1.f);
  c = sF * c + sI * tG;
  const float tC =
      1.f - 2.f * __builtin_amdgcn_rcpf(__builtin_amdgcn_exp2f((2.f * L2E) * c) + 1.f);
  h = sO * tC;
}

// Recurrent step: gates = W*h + gx (gx holds input-proj + bias from the ring).
__device__ __forceinline__ void rec_step(float gxA, float gxB, const float* WAr,
                                         const float* WBr, int lane, float& h,
                                         float& c) {
  float a0 = gxA, a1 = 0.f, b0 = gxB, b1 = 0.f;
#pragma unroll
  for (int k = 0; k < 20; k += 2) {
    const float hk0 = rdlane(h, k);
    const float hk1 = rdlane(h, k + 1);
    a0 += WAr[k] * hk0;
    a1 += WAr[k + 1] * hk1;
    b0 += WBr[k] * hk0;
    b1 += WBr[k + 1] * hk1;
  }
  lstm_update2(a0 + a1, b0 + b1, lane, h, c);
}

// Projection step: dst = W*row + bias. row = 20 floats in LDS (16B-aligned),
// read as 5 same-address float4 broadcasts (conflict-free).
__device__ __forceinline__ void proj_step(const float* row, const float* WAr,
                                          const float* WBr, float bsA, float bsB,
                                          float* dstA, float* dstB, bool wb) {
  const float4 x0 = *(const float4*)&row[0];
  const float4 x1 = *(const float4*)&row[4];
  const float4 x2 = *(const float4*)&row[8];
  const float4 x3 = *(const float4*)&row[12];
  const float4 x4 = *(const float4*)&row[16];
  float a0 = bsA, a1 = 0.f, b0 = bsB, b1 = 0.f;
  a0 += WAr[0] * x0.x;  a1 += WAr[1] * x0.y;  a0 += WAr[2] * x0.z;  a1 += WAr[3] * x0.w;
  b0 += WBr[0] * x0.x;  b1 += WBr[1] * x0.y;  b0 += WBr[2] * x0.z;  b1 += WBr[3] * x0.w;
  a0 += WAr[4] * x1.x;  a1 += WAr[5] * x1.y;  a0 += WAr[6] * x1.z;  a1 += WAr[7] * x1.w;
  b0 += WBr[4] * x1.x;  b1 += WBr[5] * x1.y;  b0 += WBr[6] * x1.z;  b1 += WBr[7] * x1.w;
  a0 += WAr[8] * x2.x;  a1 += WAr[9] * x2.y;  a0 += WAr[10] * x2.z; a1 += WAr[11] * x2.w;
  b0 += WBr[8] * x2.x;  b1 += WBr[9] * x2.y;  b0 += WBr[10] * x2.z; b1 += WBr[11] * x2.w;
  a0 += WAr[12] * x3.x; a1 += WAr[13] * x3.y; a0 += WAr[14] * x3.z; a1 += WAr[15] * x3.w;
  b0 += WBr[12] * x3.x; b1 += WBr[13] * x3.y; b0 += WBr[14] * x3.z; b1 += WBr[15] * x3.w;
  a0 += WAr[16] * x4.x; a1 += WAr[17] * x4.y; a0 += WAr[18] * x4.z; a1 += WAr[19] * x4.w;
  b0 += WBr[16] * x4.x; b1 += WBr[17] * x4.y; b0 += WBr[18] * x4.z; b1 += WBr[19] * x4.w;
  *dstA = a0 + a1;
  if (wb) *dstB = b0 + b1;
}

// One block (256 thr = 4 waves) per (g,b) chain; 512 blocks -> 2048 waves.
__global__ __launch_bounds__(256) void scan4p_kernel(
    const float* __restrict__ x, const float* __restrict__ Wih0,
    const float* __restrict__ Whh0, const float* __restrict__ bih0,
    const float* __restrict__ bhh0, const float* __restrict__ Wih1,
    const float* __restrict__ Whh1, const float* __restrict__ bih1,
    const float* __restrict__ bhh1, float* __restrict__ out) {
  __shared__ __align__(16) float XS[64][20];   // x ring: 8 chunks of 8 steps
  __shared__ __align__(16) float XW0[16][80];  // layer0 input-proj ring (2 chunks)
  __shared__ __align__(16) float XW1[16][80];  // layer1 input-proj ring (2 chunks)
  __shared__ __align__(16) float H0[16][20];   // h0 ring (2 chunks)

  const int tid = threadIdx.x;
  const int lane = tid & 63;
  const int wv = tid >> 6;
  const int chain = blockIdx.x;
  const int g = chain >> 6;
  const int b = chain & 63;
  // parity swap so each SIMD pairs a proj wave (light) with a recurrent wave (heavy)
  const int role = (chain & 1) ? (3 - wv) : wv;

  const bool wl = lane < Dn;
  const int rB = 64 + (lane & 15);
  const float sA = (lane >= 40 && lane < 60) ? (2.f * L2E) : L2E;

  // Per-role weights: A row = lane (gates 0..63), B row = 64+(lane&15).
  float WAr[20], WBr[20];
  float bsA = 0.f, bsB = 0.f;
  {
    const float* Wsrc;
    const float* bi = nullptr;
    const float* bh = nullptr;
    if (role == 0) {
      Wsrc = Wih0; bi = bih0; bh = bhh0;
    } else if (role == 1) {
      Wsrc = Whh0;
    } else if (role == 2) {
      Wsrc = Wih1; bi = bih1; bh = bhh1;
    } else {
      Wsrc = Whh1;
    }
    const float* Wg = Wsrc + g * 1600;
#pragma unroll
    for (int k = 0; k < 20; ++k) {
      WAr[k] = Wg[lane * 20 + k] * sA;
      WBr[k] = Wg[rB * 20 + k] * L2E;
    }
    if (bi) {  // bias lives in the proj roles only
      bsA = (bi[g * 80 + lane] + bh[g * 80 + lane]) * sA;
      bsB = (bi[g * 80 + rB] + bh[g * 80 + rB]) * L2E;
    }
  }

  const long long cbase = (long long)b * (Tn * Fn) + g * Dn;  // chain base in x/out

  // x-staging lane constants (role0): 160 floats per chunk over 64 lanes.
  int st_t[3], st_d[3];
  bool st_v[3];
#pragma unroll
  for (int i = 0; i < 3; ++i) {
    const int idx = lane + 64 * i;
    st_v[i] = idx < 160;
    st_t[i] = idx / 20;
    st_d[i] = idx % 20;
  }

  if (role == 0) {  // prologue: stage chunk 0
#pragma unroll
    for (int i = 0; i < 3; ++i)
      if (st_v[i])
        XS[st_t[i]][st_d[i]] = x[cbase + (long long)st_t[i] * Fn + st_d[i]];
  }
  __syncthreads();

  float h = 0.f, c = 0.f;

  // role r processes chunk (cix - r); 250 chunks of 8 steps; 1 barrier/iter.
  for (int cix = 0; cix <= 252; ++cix) {
    if (role == 0) {
      const int cs = cix + 1;  // chunk to stage this iteration
      const bool dostage = (cs <= 249);
      float sv[3];
      if (dostage) {  // issue global loads early; LDS writes after compute
#pragma unroll
        for (int i = 0; i < 3; ++i)
          if (st_v[i])
            sv[i] = x[cbase + (long long)(cs * 8 + st_t[i]) * Fn + st_d[i]];
      }
      if (cix <= 249) {
        const int c8 = cix * 8;
#pragma unroll
        for (int p = 0; p < 8; ++p) {
          const int t = c8 + p;
          proj_step(&XS[t & 63][0], WAr, WBr, bsA, bsB, &XW0[t & 15][lane],
                    &XW0[t & 15][64 + lane], lane < 16);
        }
      }
      if (dostage) {
#pragma unroll
        for (int i = 0; i < 3; ++i)
          if (st_v[i]) XS[(cs * 8 + st_t[i]) & 63][st_d[i]] = sv[i];
      }
    } else if (role == 1) {
      if (cix >= 1 && cix <= 250) {
        const int c8 = (cix - 1) * 8;
        float gxA[8], gxB[8];
#pragma unroll
        for (int p = 0; p < 8; ++p) {  // hoist ring reads off the recurrent path
          gxA[p] = XW0[(c8 + p) & 15][lane];
          gxB[p] = XW0[(c8 + p) & 15][64 + (lane & 15)];
        }
#pragma unroll
        for (int p = 0; p < 8; ++p) {
          rec_step(gxA[p], gxB[p], WAr, WBr, lane, h, c);
          if (wl) H0[(c8 + p) & 15][lane] = h;
        }
      }
    } else if (role == 2) {
      if (cix >= 2 && cix <= 251) {
        const int c8 = (cix - 2) * 8;
#pragma unroll
        for (int p = 0; p < 8; ++p) {
          const int t = c8 + p;
          proj_step(&H0[t & 15][0], WAr, WBr, bsA, bsB, &XW1[t & 15][lane],
                    &XW1[t & 15][64 + lane], lane < 16);
        }
      }
    } else {
      if (cix >= 3) {
        const int c8 = (cix - 3) * 8;
        const int rl = wl ? lane : 0;
        float gxA[8], gxB[8], xr[8];
#pragma unroll
        for (int p = 0; p < 8; ++p) {
          gxA[p] = XW1[(c8 + p) & 15][lane];
          gxB[p] = XW1[(c8 + p) & 15][64 + (lane & 15)];
          xr[p] = XS[(c8 + p) & 63][rl];  // residual x
        }
#pragma unroll
        for (int p = 0; p < 8; ++p) {
          rec_step(gxA[p], gxB[p], WAr, WBr, lane, h, c);
          if (wl) out[cbase + (long long)(c8 + p) * Fn + lane] = h + xr[p];
        }
      }
    }
    __syncthreads();  // single chunk-boundary barrier (outside role divergence)
  }
}

// ---- MFMA bf16 MLP, in place on io[NR][160] (unchanged) ----
typedef __attribute__((ext_vector_type(8))) short bf16x8;
typedef __attribute__((ext_vector_type(4))) float f32x4;

__global__ __launch_bounds__(256) void mlp_mfma_kernel(
    float* io, const float* __restrict__ W1, const float* __restrict__ b1,
    const float* __restrict__ W2, const float* __restrict__ b2) {
  __shared__ short Ab[64 * 168];
  __shared__ short Wb[64 * 168];
  __shared__ short Hb[64 * 72];
  __shared__ short W2b[160 * 72];
  const int tid = threadIdx.x;
  const int lane = tid & 63;
  const int wv = tid >> 6;
  const long long r0 = (long long)blockIdx.x * 64;

#pragma unroll
  for (int i = 0; i < 10; ++i) {
    const int idx = tid + i * 256;
    const int r = idx / 40, kq = idx % 40;
    const float4 v = *(const float4*)(io + (r0 + r) * Fn + kq * 4);
    *(ushort4*)&Ab[r * 168 + kq * 4] =
        make_ushort4(f2bf(v.x), f2bf(v.y), f2bf(v.z), f2bf(v.w));
  }
  __syncthreads();

  const int cl = lane & 15;
  const int q8 = (lane >> 4) * 8;
  const int ar = wv * 16 + cl;
  bf16x8 afr[5];
#pragma unroll
  for (int kk = 0; kk < 5; ++kk)
    afr[kk] = *(const bf16x8*)&Ab[ar * 168 + kk * 32 + q8];

  f32x4 acc[10];
#pragma unroll
  for (int n = 0; n < 10; ++n) acc[n] = (f32x4){0.f, 0.f, 0.f, 0.f};

  for (int nc = 0; nc < 10; ++nc) {
    if (nc) __syncthreads();
#pragma unroll
    for (int i = 0; i < 10; ++i) {
      const int idx = tid + i * 256;
      const int r = idx / 40, kq = idx % 40;
      const float4 v = *(const float4*)(W1 + (nc * 64 + r) * Fn + kq * 4);
      *(ushort4*)&Wb[r * 168 + kq * 4] =
          make_ushort4(f2bf(v.x), f2bf(v.y), f2bf(v.z), f2bf(v.w));
    }
#pragma unroll
    for (int i = 0; i < 10; ++i) {
      const int idx = tid + i * 256;
      const int n = idx >> 4, kq = idx & 15;
      const float4 v = *(const float4*)(W2 + n * 640 + nc * 64 + kq * 4);
      *(ushort4*)&W2b[n * 72 + kq * 4] =
          make_ushort4(f2bf(v.x), f2bf(v.y), f2bf(v.z), f2bf(v.w));
    }
    __syncthreads();
#pragma unroll
    for (int n16 = 0; n16 < 4; ++n16) {
      f32x4 hcc = (f32x4){0.f, 0.f, 0.f, 0.f};
      const int br = n16 * 16 + cl;
#pragma unroll
      for (int kk = 0; kk < 5; ++kk) {
        const bf16x8 bfr = *(const bf16x8*)&Wb[br * 168 + kk * 32 + q8];
        hcc = __builtin_amdgcn_mfma_f32_16x16x32_bf16(afr[kk], bfr, hcc, 0, 0, 0);
      }
      const float b1v = b1[nc * 64 + n16 * 16 + cl];
      const int hrow0 = wv * 16 + (lane >> 4) * 4;
      const int hcol = n16 * 16 + cl;
#pragma unroll
      for (int r = 0; r < 4; ++r)
        Hb[(hrow0 + r) * 72 + hcol] = f2bf(fmaxf(hcc[r] + b1v, 0.f));
    }
    bf16x8 a2[2];
#pragma unroll
    for (int kk = 0; kk < 2; ++kk)
      a2[kk] = *(const bf16x8*)&Hb[ar * 72 + kk * 32 + q8];
#pragma unroll
    for (int n16 = 0; n16 < 10; ++n16) {
      const int br = n16 * 16 + cl;
#pragma unroll
      for (int kk = 0; kk < 2; ++kk) {
        const bf16x8 b2f = *(const bf16x8*)&W2b[br * 72 + kk * 32 + q8];
        acc[n16] = __builtin_amdgcn_mfma_f32_16x16x32_bf16(a2[kk], b2f, acc[n16], 0, 0, 0);
      }
    }
  }
  const int orow0 = wv * 16 + (lane >> 4) * 4;
#pragma unroll
  for (int n16 = 0; n16 < 10; ++n16) {
    const float b2v = b2[n16 * 16 + cl];
#pragma unroll
    for (int r = 0; r < 4; ++r)
      io[(r0 + orow0 + r) * Fn + n16 * 16 + cl] = acc[n16][r] + b2v;
  }
}

extern "C" void kernel_launch(void* const* d_in, const int* in_sizes, int n_in,
                              void* d_out, int out_size, void* d_ws, size_t ws_size,
                              hipStream_t stream) {
  const float* x    = (const float*)d_in[0];
  const float* Wih0 = (const float*)d_in[1];
  const float* Whh0 = (const float*)d_in[2];
  const float* bih0 = (const float*)d_in[3];
  const float* bhh0 = (const float*)d_in[4];
  const float* Wih1 = (const float*)d_in[5];
  const float* Whh1 = (const float*)d_in[6];
  const float* bih1 = (const float*)d_in[7];
  const float* bhh1 = (const float*)d_in[8];
  const float* W1   = (const float*)d_in[9];
  const float* b1   = (const float*)d_in[10];
  const float* W2   = (const float*)d_in[11];
  const float* b2   = (const float*)d_in[12];
  float* out = (float*)d_out;
  (void)d_ws; (void)ws_size;

  scan4p_kernel<<<dim3(512), dim3(256), 0, stream>>>(
      x, Wih0, Whh0, bih0, bhh0, Wih1, Whh1, bih1, bhh1, out);
  mlp_mfma_kernel<<<dim3(NR / 64), dim3(256), 0, stream>>>(out, W1, b1, W2, b2);
}

// Round 3
// 842.072 us; speedup vs baseline: 1.2391x; 1.0616x over previous
//
#include <hip/hip_runtime.h>

// SubLSTM R7: R6 structure with the two unproven asm primitives replaced by
// safe equivalents (one-risky-change-at-a-time recovery from R6's fail):
//  - Gate-row remap kept: A-slot {i@lanes0-19, f@lanes32-51}, B-slot
//    {g@0-19, o@32-51}. Cross-lane moves are lane<->lane^32, now via
//    __shfl_xor(v,32) (2 shuffles/step vs R5's 4, issued back-to-back).
//  - log2e folded into weights/biases: 6 transcendentals/step (was 10).
//  - Plain scalar FMA dots (R5-proven); no v_pk_fma_f32 asm, no permlane asm.
//  - 4-role pipeline, rings, setprio(1) on recurrent roles: unchanged from R6.
// mlp_mfma unchanged.

#define Gn 8
#define Dn 20
#define Bn 64
#define Tn 2000
#define Fn 160
#define NR (Bn * Tn)
#define L2E 1.4426950408889634f

typedef __attribute__((ext_vector_type(4))) float f32x4;
typedef __attribute__((ext_vector_type(8))) short bf16x8;

__device__ __forceinline__ float rdlane(float v, int k) {
  return __int_as_float(__builtin_amdgcn_readlane(__float_as_int(v), k));
}
__device__ __forceinline__ float xswap(float v) {  // lane <-> lane^32
  return __shfl_xor(v, 32);
}
__device__ __forceinline__ unsigned short f2bf(float f) {
  unsigned u = __float_as_uint(f);
  u += 0x8000u;
  return (unsigned short)(u >> 16);
}

// Recurrent step. gzA/gzB: prescaled input-proj+bias from ring. h,c updated.
// Lanes 0..19 hold the real state; other lanes compute bounded garbage.
// A rows (i,f) and B o rows prescaled by -log2e; B g rows by +2*log2e.
__device__ __forceinline__ void rec2(float gzA, float gzB,
                                     const float* __restrict__ WA,
                                     const float* __restrict__ WB, float& h,
                                     float& c) {
  float hk[20];
#pragma unroll
  for (int k = 0; k < 20; ++k) hk[k] = rdlane(h, k);
  float a0 = gzA, a1 = 0.f, b0 = gzB, b1 = 0.f;
#pragma unroll
  for (int k = 0; k < 20; k += 2) {
    a0 = __builtin_fmaf(WA[k], hk[k], a0);
    a1 = __builtin_fmaf(WA[k + 1], hk[k + 1], a1);
    b0 = __builtin_fmaf(WB[k], hk[k], b0);
    b1 = __builtin_fmaf(WB[k + 1], hk[k + 1], b1);
  }
  const float zA = a0 + a1;
  const float zB = b0 + b1;
  const float rA = __builtin_amdgcn_rcpf(1.f + __builtin_amdgcn_exp2f(zA));
  const float rB = __builtin_amdgcn_rcpf(1.f + __builtin_amdgcn_exp2f(zB));
  const float sF = xswap(rA);  // f-sigmoid for lanes 0..19
  const float sO = xswap(rB);  // o-sigmoid for lanes 0..19
  const float tG = __builtin_fmaf(-2.f, rB, 1.f);  // tanh(g), own lane
  c = sF * c + rA * tG;                            // sI = rA (own lane)
  const float tC = __builtin_fmaf(
      -2.f, __builtin_amdgcn_rcpf(1.f + __builtin_amdgcn_exp2f((2.f * L2E) * c)),
      1.f);
  h = sO * tC;
}

// Projection step: z = W*row + bias (prescaled), row = 20 floats in LDS
// (16B-aligned), read as 5 same-address float4 broadcasts (conflict-free).
__device__ __forceinline__ void proj2(const float* __restrict__ row,
                                      const float* __restrict__ WA,
                                      const float* __restrict__ WB, float bzA,
                                      float bzB, float* dA, float* dB) {
  const f32x4 x0 = *(const f32x4*)&row[0];
  const f32x4 x1 = *(const f32x4*)&row[4];
  const f32x4 x2 = *(const f32x4*)&row[8];
  const f32x4 x3 = *(const f32x4*)&row[12];
  const f32x4 x4 = *(const f32x4*)&row[16];
  float xk[20];
  xk[0] = x0.x; xk[1] = x0.y; xk[2] = x0.z; xk[3] = x0.w;
  xk[4] = x1.x; xk[5] = x1.y; xk[6] = x1.z; xk[7] = x1.w;
  xk[8] = x2.x; xk[9] = x2.y; xk[10] = x2.z; xk[11] = x2.w;
  xk[12] = x3.x; xk[13] = x3.y; xk[14] = x3.z; xk[15] = x3.w;
  xk[16] = x4.x; xk[17] = x4.y; xk[18] = x4.z; xk[19] = x4.w;
  float a0 = bzA, a1 = 0.f, b0 = bzB, b1 = 0.f;
#pragma unroll
  for (int k = 0; k < 20; k += 2) {
    a0 = __builtin_fmaf(WA[k], xk[k], a0);
    a1 = __builtin_fmaf(WA[k + 1], xk[k + 1], a1);
    b0 = __builtin_fmaf(WB[k], xk[k], b0);
    b1 = __builtin_fmaf(WB[k + 1], xk[k + 1], b1);
  }
  *dA = a0 + a1;
  *dB = b0 + b1;
}

// One block (256 thr = 4 waves) per (g,b) chain; 512 blocks -> 2048 waves.
__global__ __launch_bounds__(256) void scan4p_kernel(
    const float* __restrict__ x, const float* __restrict__ Wih0,
    const float* __restrict__ Whh0, const float* __restrict__ bih0,
    const float* __restrict__ bhh0, const float* __restrict__ Wih1,
    const float* __restrict__ Whh1, const float* __restrict__ bih1,
    const float* __restrict__ bhh1, float* __restrict__ out) {
  __shared__ __align__(16) float XS[64][20];    // x ring: 8 chunks of 8 steps
  __shared__ __align__(16) float XW0[16][128];  // layer0 input-proj ring (2 chunks)
  __shared__ __align__(16) float XW1[16][128];  // layer1 input-proj ring (2 chunks)
  __shared__ __align__(16) float H0[16][20];    // h0 ring (2 chunks)

  const int tid = threadIdx.x;
  const int lane = tid & 63;
  const int wv = tid >> 6;
  const int chain = blockIdx.x;
  const int g = chain >> 6;
  const int b = chain & 63;
  // parity swap so each SIMD pairs a proj wave (light) with a recurrent wave
  const int role = (chain & 1) ? (3 - wv) : wv;

  const bool wl = lane < Dn;

  // Gate-row remap: A rows {i: lanes 0..19 -> row d; f: lanes 32..51 -> row 20+d}
  //                 B rows {g: lanes 0..19 -> row 40+d; o: lanes 32..51 -> row 60+d}
  int rowA, rowB;
  float sAc, sBc;
  if (lane < 20) {
    rowA = lane; rowB = lane + 40; sAc = -L2E; sBc = 2.f * L2E;
  } else if (lane >= 32 && lane < 52) {
    rowA = lane - 12; rowB = lane + 28; sAc = -L2E; sBc = -L2E;
  } else {
    rowA = 0; rowB = 0; sAc = 0.f; sBc = 0.f;
  }

  float WA[20], WB[20];
  float bzA = 0.f, bzB = 0.f;
  {
    const float* Wsrc;
    const float* bi = nullptr;
    const float* bh = nullptr;
    if (role == 0) {
      Wsrc = Wih0; bi = bih0; bh = bhh0;
    } else if (role == 1) {
      Wsrc = Whh0;
    } else if (role == 2) {
      Wsrc = Wih1; bi = bih1; bh = bhh1;
    } else {
      Wsrc = Whh1;
    }
    const float* Wg = Wsrc + g * 1600;
#pragma unroll
    for (int k = 0; k < 20; ++k) {
      WA[k] = Wg[rowA * 20 + k] * sAc;
      WB[k] = Wg[rowB * 20 + k] * sBc;
    }
    if (bi) {
      bzA = (bi[g * 80 + rowA] + bh[g * 80 + rowA]) * sAc;
      bzB = (bi[g * 80 + rowB] + bh[g * 80 + rowB]) * sBc;
    }
  }

  if (role & 1) __builtin_amdgcn_s_setprio(1);  // favor the recurrent waves

  const long long cbase = (long long)b * (Tn * Fn) + g * Dn;

  // x-staging lane constants (role0): 160 floats per chunk over 64 lanes.
  int st_t[3], st_d[3];
  bool st_v[3];
#pragma unroll
  for (int i = 0; i < 3; ++i) {
    const int idx = lane + 64 * i;
    st_v[i] = idx < 160;
    st_t[i] = idx / 20;
    st_d[i] = idx % 20;
  }

  if (role == 0) {  // prologue: stage chunk 0
#pragma unroll
    for (int i = 0; i < 3; ++i)
      if (st_v[i])
        XS[st_t[i]][st_d[i]] = x[cbase + (long long)st_t[i] * Fn + st_d[i]];
  }
  __syncthreads();

  float h = 0.f, c = 0.f;

  // role r processes chunk (cix - r); 250 chunks of 8 steps; 1 barrier/iter.
  for (int cix = 0; cix <= 252; ++cix) {
    if (role == 0) {
      const int cs = cix + 1;  // chunk to stage this iteration
      const bool dostage = (cs <= 249);
      float sv[3];
      if (dostage) {  // issue global loads early; LDS writes after compute
#pragma unroll
        for (int i = 0; i < 3; ++i)
          if (st_v[i])
            sv[i] = x[cbase + (long long)(cs * 8 + st_t[i]) * Fn + st_d[i]];
      }
      if (cix <= 249) {
        const float* xsp = &XS[(cix * 8) & 63][0];
        float* xwp = &XW0[(cix * 8) & 15][0];
#pragma unroll
        for (int p = 0; p < 8; ++p)
          proj2(&xsp[p * 20], WA, WB, bzA, bzB, &xwp[p * 128 + lane],
                &xwp[p * 128 + 64 + lane]);
      }
      if (dostage) {
        float* xsw = &XS[(cs * 8) & 63][0];
#pragma unroll
        for (int i = 0; i < 3; ++i)
          if (st_v[i]) xsw[st_t[i] * 20 + st_d[i]] = sv[i];
      }
    } else if (role == 1) {
      if (cix >= 1 && cix <= 250) {
        const float* xwp = &XW0[((cix - 1) * 8) & 15][0];
        float* hrw = &H0[((cix - 1) * 8) & 15][0];
        float gzA[8], gzB[8];
#pragma unroll
        for (int p = 0; p < 8; ++p) {  // hoist ring reads off the serial path
          gzA[p] = xwp[p * 128 + lane];
          gzB[p] = xwp[p * 128 + 64 + lane];
        }
#pragma unroll
        for (int p = 0; p < 8; ++p) {
          rec2(gzA[p], gzB[p], WA, WB, h, c);
          if (wl) hrw[p * 20 + lane] = h;
        }
      }
    } else if (role == 2) {
      if (cix >= 2 && cix <= 251) {
        const float* hrp = &H0[((cix - 2) * 8) & 15][0];
        float* xwp = &XW1[((cix - 2) * 8) & 15][0];
#pragma unroll
        for (int p = 0; p < 8; ++p)
          proj2(&hrp[p * 20], WA, WB, bzA, bzB, &xwp[p * 128 + lane],
                &xwp[p * 128 + 64 + lane]);
      }
    } else {
      if (cix >= 3) {
        const int c8 = (cix - 3) * 8;
        const int rl = wl ? lane : 0;
        const float* xwp = &XW1[c8 & 15][0];
        const float* xsp = &XS[c8 & 63][0];
        float gzA[8], gzB[8], xr[8];
#pragma unroll
        for (int p = 0; p < 8; ++p) {
          gzA[p] = xwp[p * 128 + lane];
          gzB[p] = xwp[p * 128 + 64 + (lane & 63)];
          xr[p] = xsp[p * 20 + rl];  // residual x
        }
#pragma unroll
        for (int p = 0; p < 8; ++p) {
          rec2(gzA[p], gzB[p], WA, WB, h, c);
          if (wl) out[cbase + (long long)(c8 + p) * Fn + lane] = h + xr[p];
        }
      }
    }
    __syncthreads();  // single chunk-boundary barrier (outside role divergence)
  }
}

// ---- MFMA bf16 MLP, in place on io[NR][160] (unchanged) ----
__global__ __launch_bounds__(256) void mlp_mfma_kernel(
    float* io, const float* __restrict__ W1, const float* __restrict__ b1,
    const float* __restrict__ W2, const float* __restrict__ b2) {
  __shared__ short Ab[64 * 168];
  __shared__ short Wb[64 * 168];
  __shared__ short Hb[64 * 72];
  __shared__ short W2b[160 * 72];
  const int tid = threadIdx.x;
  const int lane = tid & 63;
  const int wv = tid >> 6;
  const long long r0 = (long long)blockIdx.x * 64;

#pragma unroll
  for (int i = 0; i < 10; ++i) {
    const int idx = tid + i * 256;
    const int r = idx / 40, kq = idx % 40;
    const float4 v = *(const float4*)(io + (r0 + r) * Fn + kq * 4);
    *(ushort4*)&Ab[r * 168 + kq * 4] =
        make_ushort4(f2bf(v.x), f2bf(v.y), f2bf(v.z), f2bf(v.w));
  }
  __syncthreads();

  const int cl = lane & 15;
  const int q8 = (lane >> 4) * 8;
  const int ar = wv * 16 + cl;
  bf16x8 afr[5];
#pragma unroll
  for (int kk = 0; kk < 5; ++kk)
    afr[kk] = *(const bf16x8*)&Ab[ar * 168 + kk * 32 + q8];

  f32x4 acc[10];
#pragma unroll
  for (int n = 0; n < 10; ++n) acc[n] = (f32x4){0.f, 0.f, 0.f, 0.f};

  for (int nc = 0; nc < 10; ++nc) {
    if (nc) __syncthreads();
#pragma unroll
    for (int i = 0; i < 10; ++i) {
      const int idx = tid + i * 256;
      const int r = idx / 40, kq = idx % 40;
      const float4 v = *(const float4*)(W1 + (nc * 64 + r) * Fn + kq * 4);
      *(ushort4*)&Wb[r * 168 + kq * 4] =
          make_ushort4(f2bf(v.x), f2bf(v.y), f2bf(v.z), f2bf(v.w));
    }
#pragma unroll
    for (int i = 0; i < 10; ++i) {
      const int idx = tid + i * 256;
      const int n = idx >> 4, kq = idx & 15;
      const float4 v = *(const float4*)(W2 + n * 640 + nc * 64 + kq * 4);
      *(ushort4*)&W2b[n * 72 + kq * 4] =
          make_ushort4(f2bf(v.x), f2bf(v.y), f2bf(v.z), f2bf(v.w));
    }
    __syncthreads();
#pragma unroll
    for (int n16 = 0; n16 < 4; ++n16) {
      f32x4 hcc = (f32x4){0.f, 0.f, 0.f, 0.f};
      const int br = n16 * 16 + cl;
#pragma unroll
      for (int kk = 0; kk < 5; ++kk) {
        const bf16x8 bfr = *(const bf16x8*)&Wb[br * 168 + kk * 32 + q8];
        hcc = __builtin_amdgcn_mfma_f32_16x16x32_bf16(afr[kk], bfr, hcc, 0, 0, 0);
      }
      const float b1v = b1[nc * 64 + n16 * 16 + cl];
      const int hrow0 = wv * 16 + (lane >> 4) * 4;
      const int hcol = n16 * 16 + cl;
#pragma unroll
      for (int r = 0; r < 4; ++r)
        Hb[(hrow0 + r) * 72 + hcol] = f2bf(fmaxf(hcc[r] + b1v, 0.f));
    }
    bf16x8 a2[2];
#pragma unroll
    for (int kk = 0; kk < 2; ++kk)
      a2[kk] = *(const bf16x8*)&Hb[ar * 72 + kk * 32 + q8];
#pragma unroll
    for (int n16 = 0; n16 < 10; ++n16) {
      const int br = n16 * 16 + cl;
#pragma unroll
      for (int kk = 0; kk < 2; ++kk) {
        const bf16x8 b2f = *(const bf16x8*)&W2b[br * 72 + kk * 32 + q8];
        acc[n16] = __builtin_amdgcn_mfma_f32_16x16x32_bf16(a2[kk], b2f, acc[n16], 0, 0, 0);
      }
    }
  }
  const int orow0 = wv * 16 + (lane >> 4) * 4;
#pragma unroll
  for (int n16 = 0; n16 < 10; ++n16) {
    const float b2v = b2[n16 * 16 + cl];
#pragma unroll
    for (int r = 0; r < 4; ++r)
      io[(r0 + orow0 + r) * Fn + n16 * 16 + cl] = acc[n16][r] + b2v;
  }
}

extern "C" void kernel_launch(void* const* d_in, const int* in_sizes, int n_in,
                              void* d_out, int out_size, void* d_ws, size_t ws_size,
                              hipStream_t stream) {
  const float* x    = (const float*)d_in[0];
  const float* Wih0 = (const float*)d_in[1];
  const float* Whh0 = (const float*)d_in[2];
  const float* bih0 = (const float*)d_in[3];
  const float* bhh0 = (const float*)d_in[4];
  const float* Wih1 = (const float*)d_in[5];
  const float* Whh1 = (const float*)d_in[6];
  const float* bih1 = (const float*)d_in[7];
  const float* bhh1 = (const float*)d_in[8];
  const float* W1   = (const float*)d_in[9];
  const float* b1   = (const float*)d_in[10];
  const float* W2   = (const float*)d_in[11];
  const float* b2   = (const float*)d_in[12];
  float* out = (float*)d_out;
  (void)d_ws; (void)ws_size;

  scan4p_kernel<<<dim3(512), dim3(256), 0, stream>>>(
      x, Wih0, Whh0, bih0, bhh0, Wih1, Whh1, bih1, bhh1, out);
  mlp_mfma_kernel<<<dim3(NR / 64), dim3(256), 0, stream>>>(out, W1, b1, W2, b2);
}

// Round 4
// 793.527 us; speedup vs baseline: 1.3149x; 1.0612x over previous
//
#include <hip/hip_runtime.h>

// SubLSTM R8: guaranteed heterogeneous role pairing + permlane32_swap.
//  - 2 chains per block, 8 waves (512 thr), 256 blocks. Wave i and i+4 share
//    a SIMD; chain0 roles = wr, chain1 roles = 3-wr -> every SIMD hosts one
//    proj wave + one rec wave BY CONSTRUCTION (no dispatch-order assumption;
//    R7's chain-parity trick paired same-parity co-resident blocks -> rec+rec
//    SIMDs paced the kernel).
//  - xswap via __builtin_amdgcn_permlane32_swap (VALU-rate half-swap) instead
//    of __shfl_xor/ds_bpermute (~60-100cy LDS latency on the serial h-chain).
//    vsrc_new[lane<32] = vdst_old[lane+32] -> take .y; consumed lanes are 0..19.
//  - Everything else identical to R7 (4-role pipeline, log2e folding, scalar
//    FMA dots, setprio on rec waves, Kc=8).
// mlp_mfma unchanged.

#define Gn 8
#define Dn 20
#define Bn 64
#define Tn 2000
#define Fn 160
#define NR (Bn * Tn)
#define L2E 1.4426950408889634f

typedef __attribute__((ext_vector_type(4))) float f32x4;
typedef __attribute__((ext_vector_type(8))) short bf16x8;
typedef __attribute__((ext_vector_type(2))) unsigned u32x2;

__device__ __forceinline__ float rdlane(float v, int k) {
  return __int_as_float(__builtin_amdgcn_readlane(__float_as_int(v), k));
}
__device__ __forceinline__ float xswap(float v) {  // v[lane^32] on lanes 0..31
#if __has_builtin(__builtin_amdgcn_permlane32_swap)
  const u32x2 r = __builtin_amdgcn_permlane32_swap(__float_as_uint(v),
                                                   __float_as_uint(v), false,
                                                   false);
  return __uint_as_float(r.y);  // new vsrc: [lane<32] = old vdst[lane+32]
#else
  return __shfl_xor(v, 32);
#endif
}
__device__ __forceinline__ unsigned short f2bf(float f) {
  unsigned u = __float_as_uint(f);
  u += 0x8000u;
  return (unsigned short)(u >> 16);
}

// Recurrent step. gzA/gzB: prescaled input-proj+bias from ring. h,c updated.
// Lanes 0..19 hold the real state; other lanes compute bounded garbage.
// A rows (i,f) and B o rows prescaled by -log2e; B g rows by +2*log2e.
__device__ __forceinline__ void rec2(float gzA, float gzB,
                                     const float* __restrict__ WA,
                                     const float* __restrict__ WB, float& h,
                                     float& c) {
  float hk[20];
#pragma unroll
  for (int k = 0; k < 20; ++k) hk[k] = rdlane(h, k);
  float a0 = gzA, a1 = 0.f, b0 = gzB, b1 = 0.f;
#pragma unroll
  for (int k = 0; k < 20; k += 2) {
    a0 = __builtin_fmaf(WA[k], hk[k], a0);
    a1 = __builtin_fmaf(WA[k + 1], hk[k + 1], a1);
    b0 = __builtin_fmaf(WB[k], hk[k], b0);
    b1 = __builtin_fmaf(WB[k + 1], hk[k + 1], b1);
  }
  const float zA = a0 + a1;
  const float zB = b0 + b1;
  const float rA = __builtin_amdgcn_rcpf(1.f + __builtin_amdgcn_exp2f(zA));
  const float rB = __builtin_amdgcn_rcpf(1.f + __builtin_amdgcn_exp2f(zB));
  const float sF = xswap(rA);  // f-sigmoid for lanes 0..19
  const float sO = xswap(rB);  // o-sigmoid for lanes 0..19
  const float tG = __builtin_fmaf(-2.f, rB, 1.f);  // tanh(g), own lane
  c = sF * c + rA * tG;                            // sI = rA (own lane)
  const float tC = __builtin_fmaf(
      -2.f, __builtin_amdgcn_rcpf(1.f + __builtin_amdgcn_exp2f((2.f * L2E) * c)),
      1.f);
  h = sO * tC;
}

// Projection step: z = W*row + bias (prescaled), row = 20 floats in LDS
// (16B-aligned), read as 5 same-address float4 broadcasts (conflict-free).
__device__ __forceinline__ void proj2(const float* __restrict__ row,
                                      const float* __restrict__ WA,
                                      const float* __restrict__ WB, float bzA,
                                      float bzB, float* dA, float* dB) {
  const f32x4 x0 = *(const f32x4*)&row[0];
  const f32x4 x1 = *(const f32x4*)&row[4];
  const f32x4 x2 = *(const f32x4*)&row[8];
  const f32x4 x3 = *(const f32x4*)&row[12];
  const f32x4 x4 = *(const f32x4*)&row[16];
  float xk[20];
  xk[0] = x0.x; xk[1] = x0.y; xk[2] = x0.z; xk[3] = x0.w;
  xk[4] = x1.x; xk[5] = x1.y; xk[6] = x1.z; xk[7] = x1.w;
  xk[8] = x2.x; xk[9] = x2.y; xk[10] = x2.z; xk[11] = x2.w;
  xk[12] = x3.x; xk[13] = x3.y; xk[14] = x3.z; xk[15] = x3.w;
  xk[16] = x4.x; xk[17] = x4.y; xk[18] = x4.z; xk[19] = x4.w;
  float a0 = bzA, a1 = 0.f, b0 = bzB, b1 = 0.f;
#pragma unroll
  for (int k = 0; k < 20; k += 2) {
    a0 = __builtin_fmaf(WA[k], xk[k], a0);
    a1 = __builtin_fmaf(WA[k + 1], xk[k + 1], a1);
    b0 = __builtin_fmaf(WB[k], xk[k], b0);
    b1 = __builtin_fmaf(WB[k + 1], xk[k + 1], b1);
  }
  *dA = a0 + a1;
  *dB = b0 + b1;
}

// One block (512 thr = 8 waves) per 2 chains; 256 blocks -> 2048 waves.
__global__ __launch_bounds__(512) void scan4p_kernel(
    const float* __restrict__ x, const float* __restrict__ Wih0,
    const float* __restrict__ Whh0, const float* __restrict__ bih0,
    const float* __restrict__ bhh0, const float* __restrict__ Wih1,
    const float* __restrict__ Whh1, const float* __restrict__ bih1,
    const float* __restrict__ bhh1, float* __restrict__ out) {
  __shared__ __align__(16) float XS[2][64][20];    // x ring: 8 chunks of 8 steps
  __shared__ __align__(16) float XW0[2][16][128];  // layer0 input-proj ring
  __shared__ __align__(16) float XW1[2][16][128];  // layer1 input-proj ring
  __shared__ __align__(16) float H0[2][16][20];    // h0 ring

  const int tid = threadIdx.x;
  const int lane = tid & 63;
  const int wv = tid >> 6;  // 0..7
  const int sub = wv >> 2;  // chain-in-block
  const int wr = wv & 3;
  const int role = sub ? (3 - wr) : wr;  // SIMD i gets {chain0 role i, chain1 role 3-i}
  const int chain = blockIdx.x * 2 + sub;
  const int g = chain >> 6;
  const int b = chain & 63;

  float (*const xs)[20] = XS[sub];
  float (*const xw0)[128] = XW0[sub];
  float (*const xw1)[128] = XW1[sub];
  float (*const h0r)[20] = H0[sub];

  const bool wl = lane < Dn;

  // Gate-row remap: A rows {i: lanes 0..19 -> row d; f: lanes 32..51 -> row 20+d}
  //                 B rows {g: lanes 0..19 -> row 40+d; o: lanes 32..51 -> row 60+d}
  int rowA, rowB;
  float sAc, sBc;
  if (lane < 20) {
    rowA = lane; rowB = lane + 40; sAc = -L2E; sBc = 2.f * L2E;
  } else if (lane >= 32 && lane < 52) {
    rowA = lane - 12; rowB = lane + 28; sAc = -L2E; sBc = -L2E;
  } else {
    rowA = 0; rowB = 0; sAc = 0.f; sBc = 0.f;
  }

  float WA[20], WB[20];
  float bzA = 0.f, bzB = 0.f;
  {
    const float* Wsrc;
    const float* bi = nullptr;
    const float* bh = nullptr;
    if (role == 0) {
      Wsrc = Wih0; bi = bih0; bh = bhh0;
    } else if (role == 1) {
      Wsrc = Whh0;
    } else if (role == 2) {
      Wsrc = Wih1; bi = bih1; bh = bhh1;
    } else {
      Wsrc = Whh1;
    }
    const float* Wg = Wsrc + g * 1600;
#pragma unroll
    for (int k = 0; k < 20; ++k) {
      WA[k] = Wg[rowA * 20 + k] * sAc;
      WB[k] = Wg[rowB * 20 + k] * sBc;
    }
    if (bi) {
      bzA = (bi[g * 80 + rowA] + bh[g * 80 + rowA]) * sAc;
      bzB = (bi[g * 80 + rowB] + bh[g * 80 + rowB]) * sBc;
    }
  }

  if (role & 1) __builtin_amdgcn_s_setprio(1);  // favor the recurrent waves

  const long long cbase = (long long)b * (Tn * Fn) + g * Dn;

  // x-staging lane constants (role0): 160 floats per chunk over 64 lanes.
  int st_t[3], st_d[3];
  bool st_v[3];
#pragma unroll
  for (int i = 0; i < 3; ++i) {
    const int idx = lane + 64 * i;
    st_v[i] = idx < 160;
    st_t[i] = idx / 20;
    st_d[i] = idx % 20;
  }

  if (role == 0) {  // prologue: stage chunk 0
#pragma unroll
    for (int i = 0; i < 3; ++i)
      if (st_v[i])
        xs[st_t[i]][st_d[i]] = x[cbase + (long long)st_t[i] * Fn + st_d[i]];
  }
  __syncthreads();

  float h = 0.f, c = 0.f;

  // role r processes chunk (cix - r); 250 chunks of 8 steps; 1 barrier/iter.
  for (int cix = 0; cix <= 252; ++cix) {
    if (role == 0) {
      const int cs = cix + 1;  // chunk to stage this iteration
      const bool dostage = (cs <= 249);
      float sv[3];
      if (dostage) {  // issue global loads early; LDS writes after compute
#pragma unroll
        for (int i = 0; i < 3; ++i)
          if (st_v[i])
            sv[i] = x[cbase + (long long)(cs * 8 + st_t[i]) * Fn + st_d[i]];
      }
      if (cix <= 249) {
        const float* xsp = &xs[(cix * 8) & 63][0];
        float* xwp = &xw0[(cix * 8) & 15][0];
#pragma unroll
        for (int p = 0; p < 8; ++p)
          proj2(&xsp[p * 20], WA, WB, bzA, bzB, &xwp[p * 128 + lane],
                &xwp[p * 128 + 64 + lane]);
      }
      if (dostage) {
        float* xsw = &xs[(cs * 8) & 63][0];
#pragma unroll
        for (int i = 0; i < 3; ++i)
          if (st_v[i]) xsw[st_t[i] * 20 + st_d[i]] = sv[i];
      }
    } else if (role == 1) {
      if (cix >= 1 && cix <= 250) {
        const float* xwp = &xw0[((cix - 1) * 8) & 15][0];
        float* hrw = &h0r[((cix - 1) * 8) & 15][0];
        float gzA[8], gzB[8];
#pragma unroll
        for (int p = 0; p < 8; ++p) {  // hoist ring reads off the serial path
          gzA[p] = xwp[p * 128 + lane];
          gzB[p] = xwp[p * 128 + 64 + lane];
        }
#pragma unroll
        for (int p = 0; p < 8; ++p) {
          rec2(gzA[p], gzB[p], WA, WB, h, c);
          if (wl) hrw[p * 20 + lane] = h;
        }
      }
    } else if (role == 2) {
      if (cix >= 2 && cix <= 251) {
        const float* hrp = &h0r[((cix - 2) * 8) & 15][0];
        float* xwp = &xw1[((cix - 2) * 8) & 15][0];
#pragma unroll
        for (int p = 0; p < 8; ++p)
          proj2(&hrp[p * 20], WA, WB, bzA, bzB, &xwp[p * 128 + lane],
                &xwp[p * 128 + 64 + lane]);
      }
    } else {
      if (cix >= 3) {
        const int c8 = (cix - 3) * 8;
        const int rl = wl ? lane : 0;
        const float* xwp = &xw1[c8 & 15][0];
        const float* xsp = &xs[c8 & 63][0];
        float gzA[8], gzB[8], xr[8];
#pragma unroll
        for (int p = 0; p < 8; ++p) {
          gzA[p] = xwp[p * 128 + lane];
          gzB[p] = xwp[p * 128 + 64 + lane];
          xr[p] = xsp[p * 20 + rl];  // residual x
        }
#pragma unroll
        for (int p = 0; p < 8; ++p) {
          rec2(gzA[p], gzB[p], WA, WB, h, c);
          if (wl) out[cbase + (long long)(c8 + p) * Fn + lane] = h + xr[p];
        }
      }
    }
    __syncthreads();  // single chunk-boundary barrier (outside role divergence)
  }
}

// ---- MFMA bf16 MLP, in place on io[NR][160] (unchanged) ----
__global__ __launch_bounds__(256) void mlp_mfma_kernel(
    float* io, const float* __restrict__ W1, const float* __restrict__ b1,
    const float* __restrict__ W2, const float* __restrict__ b2) {
  __shared__ short Ab[64 * 168];
  __shared__ short Wb[64 * 168];
  __shared__ short Hb[64 * 72];
  __shared__ short W2b[160 * 72];
  const int tid = threadIdx.x;
  const int lane = tid & 63;
  const int wv = tid >> 6;
  const long long r0 = (long long)blockIdx.x * 64;

#pragma unroll
  for (int i = 0; i < 10; ++i) {
    const int idx = tid + i * 256;
    const int r = idx / 40, kq = idx % 40;
    const float4 v = *(const float4*)(io + (r0 + r) * Fn + kq * 4);
    *(ushort4*)&Ab[r * 168 + kq * 4] =
        make_ushort4(f2bf(v.x), f2bf(v.y), f2bf(v.z), f2bf(v.w));
  }
  __syncthreads();

  const int cl = lane & 15;
  const int q8 = (lane >> 4) * 8;
  const int ar = wv * 16 + cl;
  bf16x8 afr[5];
#pragma unroll
  for (int kk = 0; kk < 5; ++kk)
    afr[kk] = *(const bf16x8*)&Ab[ar * 168 + kk * 32 + q8];

  f32x4 acc[10];
#pragma unroll
  for (int n = 0; n < 10; ++n) acc[n] = (f32x4){0.f, 0.f, 0.f, 0.f};

  for (int nc = 0; nc < 10; ++nc) {
    if (nc) __syncthreads();
#pragma unroll
    for (int i = 0; i < 10; ++i) {
      const int idx = tid + i * 256;
      const int r = idx / 40, kq = idx % 40;
      const float4 v = *(const float4*)(W1 + (nc * 64 + r) * Fn + kq * 4);
      *(ushort4*)&Wb[r * 168 + kq * 4] =
          make_ushort4(f2bf(v.x), f2bf(v.y), f2bf(v.z), f2bf(v.w));
    }
#pragma unroll
    for (int i = 0; i < 10; ++i) {
      const int idx = tid + i * 256;
      const int n = idx >> 4, kq = idx & 15;
      const float4 v = *(const float4*)(W2 + n * 640 + nc * 64 + kq * 4);
      *(ushort4*)&W2b[n * 72 + kq * 4] =
          make_ushort4(f2bf(v.x), f2bf(v.y), f2bf(v.z), f2bf(v.w));
    }
    __syncthreads();
#pragma unroll
    for (int n16 = 0; n16 < 4; ++n16) {
      f32x4 hcc = (f32x4){0.f, 0.f, 0.f, 0.f};
      const int br = n16 * 16 + cl;
#pragma unroll
      for (int kk = 0; kk < 5; ++kk) {
        const bf16x8 bfr = *(const bf16x8*)&Wb[br * 168 + kk * 32 + q8];
        hcc = __builtin_amdgcn_mfma_f32_16x16x32_bf16(afr[kk], bfr, hcc, 0, 0, 0);
      }
      const float b1v = b1[nc * 64 + n16 * 16 + cl];
      const int hrow0 = wv * 16 + (lane >> 4) * 4;
      const int hcol = n16 * 16 + cl;
#pragma unroll
      for (int r = 0; r < 4; ++r)
        Hb[(hrow0 + r) * 72 + hcol] = f2bf(fmaxf(hcc[r] + b1v, 0.f));
    }
    bf16x8 a2[2];
#pragma unroll
    for (int kk = 0; kk < 2; ++kk)
      a2[kk] = *(const bf16x8*)&Hb[ar * 72 + kk * 32 + q8];
#pragma unroll
    for (int n16 = 0; n16 < 10; ++n16) {
      const int br = n16 * 16 + cl;
#pragma unroll
      for (int kk = 0; kk < 2; ++kk) {
        const bf16x8 b2f = *(const bf16x8*)&W2b[br * 72 + kk * 32 + q8];
        acc[n16] = __builtin_amdgcn_mfma_f32_16x16x32_bf16(a2[kk], b2f, acc[n16], 0, 0, 0);
      }
    }
  }
  const int orow0 = wv * 16 + (lane >> 4) * 4;
#pragma unroll
  for (int n16 = 0; n16 < 10; ++n16) {
    const float b2v = b2[n16 * 16 + cl];
#pragma unroll
    for (int r = 0; r < 4; ++r)
      io[(r0 + orow0 + r) * Fn + n16 * 16 + cl] = acc[n16][r] + b2v;
  }
}

extern "C" void kernel_launch(void* const* d_in, const int* in_sizes, int n_in,
                              void* d_out, int out_size, void* d_ws, size_t ws_size,
                              hipStream_t stream) {
  const float* x    = (const float*)d_in[0];
  const float* Wih0 = (const float*)d_in[1];
  const float* Whh0 = (const float*)d_in[2];
  const float* bih0 = (const float*)d_in[3];
  const float* bhh0 = (const float*)d_in[4];
  const float* Wih1 = (const float*)d_in[5];
  const float* Whh1 = (const float*)d_in[6];
  const float* bih1 = (const float*)d_in[7];
  const float* bhh1 = (const float*)d_in[8];
  const float* W1   = (const float*)d_in[9];
  const float* b1   = (const float*)d_in[10];
  const float* W2   = (const float*)d_in[11];
  const float* b2   = (const float*)d_in[12];
  float* out = (float*)d_out;
  (void)d_ws; (void)ws_size;

  scan4p_kernel<<<dim3(256), dim3(512), 0, stream>>>(
      x, Wih0, Whh0, bih0, bhh0, Wih1, Whh1, bih1, bhh1, out);
  mlp_mfma_kernel<<<dim3(NR / 64), dim3(256), 0, stream>>>(out, W1, b1, W2, b2);
}

// Round 6
// 711.797 us; speedup vs baseline: 1.4659x; 1.1148x over previous
//
#include <hip/hip_runtime.h>

// SubLSTM R9 (resubmit — previous run was an infra failure, not a kernel
// result): R8 + packed-f32 dots via compiler-generated v_pk_fma_f32.
//  - rec/proj 20-length dots expressed as f32x2 __builtin_elementwise_fma:
//    rec  = 20 readlane + 20 pk_fma (h-pairs are uniform -> SGPR-pair operand),
//    proj = 20 pk_fma (x-pairs alias the float4 LDS loads).
//    Compiler-generated (NOT R6's hand asm) -> op_sel/operand legality
//    guaranteed; worst case scalarizes back to R8's 40 FMA.
//  - Everything else identical to R8: 2 chains/block, 8 waves, role pairing
//    by construction (SIMD i hosts {chain0 role i, chain1 role 3-i}),
//    permlane32_swap half-swaps, log2e folding, setprio on rec waves, Kc=8.
// mlp_mfma unchanged.

#define Gn 8
#define Dn 20
#define Bn 64
#define Tn 2000
#define Fn 160
#define NR (Bn * Tn)
#define L2E 1.4426950408889634f

typedef __attribute__((ext_vector_type(2))) float f32x2;
typedef __attribute__((ext_vector_type(4))) float f32x4;
typedef __attribute__((ext_vector_type(8))) short bf16x8;
typedef __attribute__((ext_vector_type(2))) unsigned u32x2;

__device__ __forceinline__ float rdlane(float v, int k) {
  return __int_as_float(__builtin_amdgcn_readlane(__float_as_int(v), k));
}
__device__ __forceinline__ float xswap(float v) {  // v[lane^32] on lanes 0..31
#if __has_builtin(__builtin_amdgcn_permlane32_swap)
  const u32x2 r = __builtin_amdgcn_permlane32_swap(__float_as_uint(v),
                                                   __float_as_uint(v), false,
                                                   false);
  return __uint_as_float(r.y);  // new vsrc: [lane<32] = old vdst[lane+32]
#else
  return __shfl_xor(v, 32);
#endif
}
__device__ __forceinline__ unsigned short f2bf(float f) {
  unsigned u = __float_as_uint(f);
  u += 0x8000u;
  return (unsigned short)(u >> 16);
}

// Recurrent step. gzA/gzB: prescaled input-proj+bias from ring. h,c updated.
// Lanes 0..19 hold the real state; other lanes compute bounded garbage.
// A rows (i,f) and B o rows prescaled by -log2e; B g rows by +2*log2e.
__device__ __forceinline__ void rec2(float gzA, float gzB,
                                     const f32x2* __restrict__ WPA,
                                     const f32x2* __restrict__ WPB, float& h,
                                     float& c) {
  f32x2 hp[10];
#pragma unroll
  for (int j = 0; j < 10; ++j) {
    hp[j].x = rdlane(h, 2 * j);      // wave-uniform -> SGPR
    hp[j].y = rdlane(h, 2 * j + 1);  // pair -> VOP3P scalar operand
  }
  f32x2 aA;
  aA.x = gzA;
  aA.y = 0.f;
  f32x2 aB;
  aB.x = gzB;
  aB.y = 0.f;
#pragma unroll
  for (int j = 0; j < 10; ++j) {
    aA = __builtin_elementwise_fma(WPA[j], hp[j], aA);
    aB = __builtin_elementwise_fma(WPB[j], hp[j], aB);
  }
  const float zA = aA.x + aA.y;
  const float zB = aB.x + aB.y;
  const float rA = __builtin_amdgcn_rcpf(1.f + __builtin_amdgcn_exp2f(zA));
  const float rB = __builtin_amdgcn_rcpf(1.f + __builtin_amdgcn_exp2f(zB));
  const float sF = xswap(rA);  // f-sigmoid for lanes 0..19
  const float sO = xswap(rB);  // o-sigmoid for lanes 0..19
  const float tG = __builtin_fmaf(-2.f, rB, 1.f);  // tanh(g), own lane
  c = sF * c + rA * tG;                            // sI = rA (own lane)
  const float tC = __builtin_fmaf(
      -2.f, __builtin_amdgcn_rcpf(1.f + __builtin_amdgcn_exp2f((2.f * L2E) * c)),
      1.f);
  h = sO * tC;
}

// Projection step: z = W*row + bias (prescaled), row = 20 floats in LDS
// (16B-aligned), read as 5 same-address float4 broadcasts (conflict-free).
// x-pairs alias the float4 registers; dots via packed fma.
__device__ __forceinline__ void proj2(const float* __restrict__ row,
                                      const f32x2* __restrict__ WPA,
                                      const f32x2* __restrict__ WPB, float bzA,
                                      float bzB, float* dA, float* dB) {
  const f32x4 x0 = *(const f32x4*)&row[0];
  const f32x4 x1 = *(const f32x4*)&row[4];
  const f32x4 x2 = *(const f32x4*)&row[8];
  const f32x4 x3 = *(const f32x4*)&row[12];
  const f32x4 x4 = *(const f32x4*)&row[16];
  f32x2 xp[10];
  xp[0] = __builtin_shufflevector(x0, x0, 0, 1);
  xp[1] = __builtin_shufflevector(x0, x0, 2, 3);
  xp[2] = __builtin_shufflevector(x1, x1, 0, 1);
  xp[3] = __builtin_shufflevector(x1, x1, 2, 3);
  xp[4] = __builtin_shufflevector(x2, x2, 0, 1);
  xp[5] = __builtin_shufflevector(x2, x2, 2, 3);
  xp[6] = __builtin_shufflevector(x3, x3, 0, 1);
  xp[7] = __builtin_shufflevector(x3, x3, 2, 3);
  xp[8] = __builtin_shufflevector(x4, x4, 0, 1);
  xp[9] = __builtin_shufflevector(x4, x4, 2, 3);
  f32x2 aA;
  aA.x = bzA;
  aA.y = 0.f;
  f32x2 aB;
  aB.x = bzB;
  aB.y = 0.f;
#pragma unroll
  for (int j = 0; j < 10; ++j) {
    aA = __builtin_elementwise_fma(WPA[j], xp[j], aA);
    aB = __builtin_elementwise_fma(WPB[j], xp[j], aB);
  }
  *dA = aA.x + aA.y;
  *dB = aB.x + aB.y;
}

// One block (512 thr = 8 waves) per 2 chains; 256 blocks -> 2048 waves.
__global__ __launch_bounds__(512) void scan4p_kernel(
    const float* __restrict__ x, const float* __restrict__ Wih0,
    const float* __restrict__ Whh0, const float* __restrict__ bih0,
    const float* __restrict__ bhh0, const float* __restrict__ Wih1,
    const float* __restrict__ Whh1, const float* __restrict__ bih1,
    const float* __restrict__ bhh1, float* __restrict__ out) {
  __shared__ __align__(16) float XS[2][64][20];    // x ring: 8 chunks of 8 steps
  __shared__ __align__(16) float XW0[2][16][128];  // layer0 input-proj ring
  __shared__ __align__(16) float XW1[2][16][128];  // layer1 input-proj ring
  __shared__ __align__(16) float H0[2][16][20];    // h0 ring

  const int tid = threadIdx.x;
  const int lane = tid & 63;
  const int wv = tid >> 6;  // 0..7
  const int sub = wv >> 2;  // chain-in-block
  const int wr = wv & 3;
  const int role = sub ? (3 - wr) : wr;  // SIMD i: {chain0 role i, chain1 role 3-i}
  const int chain = blockIdx.x * 2 + sub;
  const int g = chain >> 6;
  const int b = chain & 63;

  float (*const xs)[20] = XS[sub];
  float (*const xw0)[128] = XW0[sub];
  float (*const xw1)[128] = XW1[sub];
  float (*const h0r)[20] = H0[sub];

  const bool wl = lane < Dn;

  // Gate-row remap: A rows {i: lanes 0..19 -> row d; f: lanes 32..51 -> row 20+d}
  //                 B rows {g: lanes 0..19 -> row 40+d; o: lanes 32..51 -> row 60+d}
  int rowA, rowB;
  float sAc, sBc;
  if (lane < 20) {
    rowA = lane; rowB = lane + 40; sAc = -L2E; sBc = 2.f * L2E;
  } else if (lane >= 32 && lane < 52) {
    rowA = lane - 12; rowB = lane + 28; sAc = -L2E; sBc = -L2E;
  } else {
    rowA = 0; rowB = 0; sAc = 0.f; sBc = 0.f;
  }

  f32x2 WPA[10], WPB[10];
  float bzA = 0.f, bzB = 0.f;
  {
    const float* Wsrc;
    const float* bi = nullptr;
    const float* bh = nullptr;
    if (role == 0) {
      Wsrc = Wih0; bi = bih0; bh = bhh0;
    } else if (role == 1) {
      Wsrc = Whh0;
    } else if (role == 2) {
      Wsrc = Wih1; bi = bih1; bh = bhh1;
    } else {
      Wsrc = Whh1;
    }
    const float* Wg = Wsrc + g * 1600;
#pragma unroll
    for (int j = 0; j < 10; ++j) {
      WPA[j].x = Wg[rowA * 20 + 2 * j] * sAc;
      WPA[j].y = Wg[rowA * 20 + 2 * j + 1] * sAc;
      WPB[j].x = Wg[rowB * 20 + 2 * j] * sBc;
      WPB[j].y = Wg[rowB * 20 + 2 * j + 1] * sBc;
    }
    if (bi) {
      bzA = (bi[g * 80 + rowA] + bh[g * 80 + rowA]) * sAc;
      bzB = (bi[g * 80 + rowB] + bh[g * 80 + rowB]) * sBc;
    }
  }

  if (role & 1) __builtin_amdgcn_s_setprio(1);  // favor the recurrent waves

  const long long cbase = (long long)b * (Tn * Fn) + g * Dn;

  // x-staging lane constants (role0): 160 floats per chunk over 64 lanes.
  int st_t[3], st_d[3];
  bool st_v[3];
#pragma unroll
  for (int i = 0; i < 3; ++i) {
    const int idx = lane + 64 * i;
    st_v[i] = idx < 160;
    st_t[i] = idx / 20;
    st_d[i] = idx % 20;
  }

  if (role == 0) {  // prologue: stage chunk 0
#pragma unroll
    for (int i = 0; i < 3; ++i)
      if (st_v[i])
        xs[st_t[i]][st_d[i]] = x[cbase + (long long)st_t[i] * Fn + st_d[i]];
  }
  __syncthreads();

  float h = 0.f, c = 0.f;

  // role r processes chunk (cix - r); 250 chunks of 8 steps; 1 barrier/iter.
  for (int cix = 0; cix <= 252; ++cix) {
    if (role == 0) {
      const int cs = cix + 1;  // chunk to stage this iteration
      const bool dostage = (cs <= 249);
      float sv[3];
      if (dostage) {  // issue global loads early; LDS writes after compute
#pragma unroll
        for (int i = 0; i < 3; ++i)
          if (st_v[i])
            sv[i] = x[cbase + (long long)(cs * 8 + st_t[i]) * Fn + st_d[i]];
      }
      if (cix <= 249) {
        const float* xsp = &xs[(cix * 8) & 63][0];
        float* xwp = &xw0[(cix * 8) & 15][0];
#pragma unroll
        for (int p = 0; p < 8; ++p)
          proj2(&xsp[p * 20], WPA, WPB, bzA, bzB, &xwp[p * 128 + lane],
                &xwp[p * 128 + 64 + lane]);
      }
      if (dostage) {
        float* xsw = &xs[(cs * 8) & 63][0];
#pragma unroll
        for (int i = 0; i < 3; ++i)
          if (st_v[i]) xsw[st_t[i] * 20 + st_d[i]] = sv[i];
      }
    } else if (role == 1) {
      if (cix >= 1 && cix <= 250) {
        const float* xwp = &xw0[((cix - 1) * 8) & 15][0];
        float* hrw = &h0r[((cix - 1) * 8) & 15][0];
        float gzA[8], gzB[8];
#pragma unroll
        for (int p = 0; p < 8; ++p) {  // hoist ring reads off the serial path
          gzA[p] = xwp[p * 128 + lane];
          gzB[p] = xwp[p * 128 + 64 + lane];
        }
#pragma unroll
        for (int p = 0; p < 8; ++p) {
          rec2(gzA[p], gzB[p], WPA, WPB, h, c);
          if (wl) hrw[p * 20 + lane] = h;
        }
      }
    } else if (role == 2) {
      if (cix >= 2 && cix <= 251) {
        const float* hrp = &h0r[((cix - 2) * 8) & 15][0];
        float* xwp = &xw1[((cix - 2) * 8) & 15][0];
#pragma unroll
        for (int p = 0; p < 8; ++p)
          proj2(&hrp[p * 20], WPA, WPB, bzA, bzB, &xwp[p * 128 + lane],
                &xwp[p * 128 + 64 + lane]);
      }
    } else {
      if (cix >= 3) {
        const int c8 = (cix - 3) * 8;
        const int rl = wl ? lane : 0;
        const float* xwp = &xw1[c8 & 15][0];
        const float* xsp = &xs[c8 & 63][0];
        float gzA[8], gzB[8], xr[8];
#pragma unroll
        for (int p = 0; p < 8; ++p) {
          gzA[p] = xwp[p * 128 + lane];
          gzB[p] = xwp[p * 128 + 64 + lane];
          xr[p] = xsp[p * 20 + rl];  // residual x
        }
#pragma unroll
        for (int p = 0; p < 8; ++p) {
          rec2(gzA[p], gzB[p], WPA, WPB, h, c);
          if (wl) out[cbase + (long long)(c8 + p) * Fn + lane] = h + xr[p];
        }
      }
    }
    __syncthreads();  // single chunk-boundary barrier (outside role divergence)
  }
}

// ---- MFMA bf16 MLP, in place on io[NR][160] (unchanged) ----
__global__ __launch_bounds__(256) void mlp_mfma_kernel(
    float* io, const float* __restrict__ W1, const float* __restrict__ b1,
    const float* __restrict__ W2, const float* __restrict__ b2) {
  __shared__ short Ab[64 * 168];
  __shared__ short Wb[64 * 168];
  __shared__ short Hb[64 * 72];
  __shared__ short W2b[160 * 72];
  const int tid = threadIdx.x;
  const int lane = tid & 63;
  const int wv = tid >> 6;
  const long long r0 = (long long)blockIdx.x * 64;

#pragma unroll
  for (int i = 0; i < 10; ++i) {
    const int idx = tid + i * 256;
    const int r = idx / 40, kq = idx % 40;
    const float4 v = *(const float4*)(io + (r0 + r) * Fn + kq * 4);
    *(ushort4*)&Ab[r * 168 + kq * 4] =
        make_ushort4(f2bf(v.x), f2bf(v.y), f2bf(v.z), f2bf(v.w));
  }
  __syncthreads();

  const int cl = lane & 15;
  const int q8 = (lane >> 4) * 8;
  const int ar = wv * 16 + cl;
  bf16x8 afr[5];
#pragma unroll
  for (int kk = 0; kk < 5; ++kk)
    afr[kk] = *(const bf16x8*)&Ab[ar * 168 + kk * 32 + q8];

  f32x4 acc[10];
#pragma unroll
  for (int n = 0; n < 10; ++n) acc[n] = (f32x4){0.f, 0.f, 0.f, 0.f};

  for (int nc = 0; nc < 10; ++nc) {
    if (nc) __syncthreads();
#pragma unroll
    for (int i = 0; i < 10; ++i) {
      const int idx = tid + i * 256;
      const int r = idx / 40, kq = idx % 40;
      const float4 v = *(const float4*)(W1 + (nc * 64 + r) * Fn + kq * 4);
      *(ushort4*)&Wb[r * 168 + kq * 4] =
          make_ushort4(f2bf(v.x), f2bf(v.y), f2bf(v.z), f2bf(v.w));
    }
#pragma unroll
    for (int i = 0; i < 10; ++i) {
      const int idx = tid + i * 256;
      const int n = idx >> 4, kq = idx & 15;
      const float4 v = *(const float4*)(W2 + n * 640 + nc * 64 + kq * 4);
      *(ushort4*)&W2b[n * 72 + kq * 4] =
          make_ushort4(f2bf(v.x), f2bf(v.y), f2bf(v.z), f2bf(v.w));
    }
    __syncthreads();
#pragma unroll
    for (int n16 = 0; n16 < 4; ++n16) {
      f32x4 hcc = (f32x4){0.f, 0.f, 0.f, 0.f};
      const int br = n16 * 16 + cl;
#pragma unroll
      for (int kk = 0; kk < 5; ++kk) {
        const bf16x8 bfr = *(const bf16x8*)&Wb[br * 168 + kk * 32 + q8];
        hcc = __builtin_amdgcn_mfma_f32_16x16x32_bf16(afr[kk], bfr, hcc, 0, 0, 0);
      }
      const float b1v = b1[nc * 64 + n16 * 16 + cl];
      const int hrow0 = wv * 16 + (lane >> 4) * 4;
      const int hcol = n16 * 16 + cl;
#pragma unroll
      for (int r = 0; r < 4; ++r)
        Hb[(hrow0 + r) * 72 + hcol] = f2bf(fmaxf(hcc[r] + b1v, 0.f));
    }
    bf16x8 a2[2];
#pragma unroll
    for (int kk = 0; kk < 2; ++kk)
      a2[kk] = *(const bf16x8*)&Hb[ar * 72 + kk * 32 + q8];
#pragma unroll
    for (int n16 = 0; n16 < 10; ++n16) {
      const int br = n16 * 16 + cl;
#pragma unroll
      for (int kk = 0; kk < 2; ++kk) {
        const bf16x8 b2f = *(const bf16x8*)&W2b[br * 72 + kk * 32 + q8];
        acc[n16] = __builtin_amdgcn_mfma_f32_16x16x32_bf16(a2[kk], b2f, acc[n16], 0, 0, 0);
      }
    }
  }
  const int orow0 = wv * 16 + (lane >> 4) * 4;
#pragma unroll
  for (int n16 = 0; n16 < 10; ++n16) {
    const float b2v = b2[n16 * 16 + cl];
#pragma unroll
    for (int r = 0; r < 4; ++r)
      io[(r0 + orow0 + r) * Fn + n16 * 16 + cl] = acc[n16][r] + b2v;
  }
}

extern "C" void kernel_launch(void* const* d_in, const int* in_sizes, int n_in,
                              void* d_out, int out_size, void* d_ws, size_t ws_size,
                              hipStream_t stream) {
  const float* x    = (const float*)d_in[0];
  const float* Wih0 = (const float*)d_in[1];
  const float* Whh0 = (const float*)d_in[2];
  const float* bih0 = (const float*)d_in[3];
  const float* bhh0 = (const float*)d_in[4];
  const float* Wih1 = (const float*)d_in[5];
  const float* Whh1 = (const float*)d_in[6];
  const float* bih1 = (const float*)d_in[7];
  const float* bhh1 = (const float*)d_in[8];
  const float* W1   = (const float*)d_in[9];
  const float* b1   = (const float*)d_in[10];
  const float* W2   = (const float*)d_in[11];
  const float* b2   = (const float*)d_in[12];
  float* out = (float*)d_out;
  (void)d_ws; (void)ws_size;

  scan4p_kernel<<<dim3(256), dim3(512), 0, stream>>>(
      x, Wih0, Whh0, bih0, bhh0, Wih1, Whh1, bih1, bhh1, out);
  mlp_mfma_kernel<<<dim3(NR / 64), dim3(256), 0, stream>>>(out, W1, b1, W2, b2);
}